// Round 14
// baseline (206.842 us; speedup 1.0000x reference)
//
#include <hip/hip_runtime.h>

// GCN: 4 layers (64->64->64->64->16), N=100k nodes, E=1.6M edges (+ self loops).
// out[i] = dis[i] * ( sum_{src->i} t[src] + t[i] ) + b,  t = dis * (h @ W)
// Round 14: r13 (200.7us) with ONLY k_binB changed: two-pass (count/reserve/
// place) over 16K-edge blocks -> per-bucket write runs 21B->84B, write-allocate
// line amplification ~7x -> ~2.5x. Gather path untouched (empirically pinned at
// the random-128B access ceiling across 5 structural variants, r10-r13).

#define BKT_SHIFT 7
#define BKT_NODES 128
#define NBMAX 800               // max buckets (n <= 102400)
#define CAP 4096                // edges per bucket window (mean 2046, max ~2300)
#define EB 16384                // edges per binB block (two-pass)

typedef __attribute__((ext_vector_type(8))) short short8;   // 8 bf16 (4 VGPRs)
typedef __attribute__((ext_vector_type(4))) float f32x4;

union U4S8 { uint4 u; short8 s; };
__device__ __forceinline__ short8 as_s8(uint4 u) { U4S8 c; c.u = u; return c.s; }

// ---- bf16 helpers ----
__device__ __forceinline__ unsigned bf16rne(float f) {
    unsigned u = __float_as_uint(f);
    return (u + 0x7FFFu + ((u >> 16) & 1u)) >> 16;
}
__device__ __forceinline__ unsigned pack2(float a, float b) {
    return bf16rne(a) | (bf16rne(b) << 16);
}
__device__ __forceinline__ float lo16(unsigned u) { return __uint_as_float(u << 16); }
__device__ __forceinline__ float hi16(unsigned u) { return __uint_as_float(u & 0xFFFF0000u); }

// ---- prep: weights f32 -> bf16 transposed + gcursor init ----
__global__ void k_prep(const float* __restrict__ W_in, const float* __restrict__ W_h,
                       const float* __restrict__ W_out, unsigned short* __restrict__ Wt,
                       int* __restrict__ gcursor, int nb) {
    int i = blockIdx.x * 256 + threadIdx.x;
    if (i < 12288) {
        int w = i >> 12, r = i & 4095;
        int col = r >> 6, k = r & 63;
        const float* Wp = (w == 0) ? W_in : W_h + (size_t)(w - 1) * 4096;
        Wt[i] = (unsigned short)bf16rne(Wp[(size_t)k * 64 + col]);
    } else if (i < 13312) {
        int r = i - 12288;
        int col = r >> 6, k = r & 63;
        Wt[i] = (unsigned short)bf16rne(W_out[(size_t)k * 16 + col]);
    }
    if (i < nb) gcursor[i] = i * CAP;
}

// ---- two-pass binning: count -> reserve -> re-read + place ----
// 16K edges/block: per-bucket runs ~21 edges (84B) -> line amp ~2.5x (was ~7x).
__global__ __launch_bounds__(512) void k_binB(const int* __restrict__ src,
                                              const int* __restrict__ dst, int e, int nb,
                                              int* __restrict__ gcursor,
                                              unsigned* __restrict__ bkt_edges) {
    __shared__ int lcnt[NBMAX];
    __shared__ int lbase[NBMAX];
    int tdx = threadIdx.x;
    for (int i = tdx; i < nb; i += 512) lcnt[i] = 0;
    __syncthreads();
    int base = blockIdx.x * EB;
    int lim = base + EB; if (lim > e) lim = e;
    // pass 1: count
    for (int i = base + tdx; i < lim; i += 512)
        atomicAdd(&lcnt[dst[i] >> BKT_SHIFT], 1);
    __syncthreads();
    // reserve global ranges
    for (int b = tdx; b < nb; b += 512) {
        int c = lcnt[b];
        lbase[b] = c ? atomicAdd(&gcursor[b], c) : 0;
        lcnt[b] = 0;
    }
    __syncthreads();
    // pass 2: place
    for (int i = base + tdx; i < lim; i += 512) {
        int s_ = src[i], d_ = dst[i];
        int bkt = d_ >> BKT_SHIFT;
        int o = atomicAdd(&lcnt[bkt], 1);
        bkt_edges[lbase[bkt] + o] = ((unsigned)s_ << BKT_SHIFT) | (unsigned)(d_ & (BKT_NODES - 1));
    }
}

// ---- per-bucket counting sort -> row_beg/row_end CSR (gapped) + dis ----
__global__ __launch_bounds__(256) void k_bsort(
    const int* __restrict__ gcursor, const unsigned* __restrict__ bkt_edges,
    int* __restrict__ row_beg, int* __restrict__ row_end, int* __restrict__ csr_src,
    float* __restrict__ dis, int n) {
    __shared__ int hist[BKT_NODES];
    __shared__ int sc[BKT_NODES];
    __shared__ int cur[BKT_NODES];
    int b = blockIdx.x, tdx = threadIdx.x;
    int beg = b * CAP;
    int end = gcursor[b];               // final cursor = beg + count
    if (tdx < BKT_NODES) hist[tdx] = 0;
    __syncthreads();
    for (int j = beg + tdx; j < end; j += 256)
        atomicAdd(&hist[bkt_edges[j] & (BKT_NODES - 1)], 1);
    __syncthreads();
    if (tdx < BKT_NODES) sc[tdx] = hist[tdx];
    __syncthreads();
    for (int off = 1; off < BKT_NODES; off <<= 1) {
        int v = (tdx < BKT_NODES && tdx >= off) ? sc[tdx - off] : 0;
        __syncthreads();
        if (tdx < BKT_NODES && tdx >= off) sc[tdx] += v;
        __syncthreads();
    }
    if (tdx < BKT_NODES) {
        int node = b * BKT_NODES + tdx;
        if (node < n) {
            int pos = beg + sc[tdx] - hist[tdx];   // exclusive prefix
            row_beg[node] = pos;
            row_end[node] = pos + hist[tdx];
            cur[tdx] = pos;
            dis[node] = rsqrtf((float)(hist[tdx] + 1));   // +1 self loop
        }
    }
    __syncthreads();
    for (int j = beg + tdx; j < end; j += 256) {
        unsigned ev = bkt_edges[j];
        int p = atomicAdd(&cur[ev & (BKT_NODES - 1)], 1);
        csr_src[p] = (int)(ev >> BKT_SHIFT);
    }
}

// ---------------- layer-1 MFMA: t = dis * (x_f32 @ W_in) ----------------
__global__ __launch_bounds__(256) void k_mmfma_x(
    const float4* __restrict__ x4,       // f32 [n][16 float4]
    const uint4* __restrict__ Wt,        // bf16 W^T, 8 uint4 per col
    const float* __restrict__ dis,
    unsigned short* __restrict__ t, int n) {
    int wave = threadIdx.x >> 6, lane = threadIdx.x & 63;
    int base = blockIdx.x * 64 + wave * 16;
    if (base >= n) return;
    int l15 = lane & 15, lq = lane >> 4;

    int arow = base + l15;
    int ac = arow < n ? arow : n - 1;            // clamp: OOB rows never stored
    const float4* xr = x4 + (size_t)ac * 16;
    float4 f0 = xr[lq * 2], f1 = xr[lq * 2 + 1];         // feats lq*8..+8
    float4 f2 = xr[8 + lq * 2], f3 = xr[9 + lq * 2];     // feats 32+lq*8..+8
    uint4 u0, u1;
    u0.x = pack2(f0.x, f0.y); u0.y = pack2(f0.z, f0.w);
    u0.z = pack2(f1.x, f1.y); u0.w = pack2(f1.z, f1.w);
    u1.x = pack2(f2.x, f2.y); u1.y = pack2(f2.z, f2.w);
    u1.z = pack2(f3.x, f3.y); u1.w = pack2(f3.z, f3.w);
    short8 a0 = as_s8(u0), a1 = as_s8(u1);

    int orow0 = base + lq * 4;
    float dn[4];
#pragma unroll
    for (int r = 0; r < 4; ++r) {
        int rr = orow0 + r;
        dn[r] = (rr < n) ? dis[rr] : 0.f;
    }
#pragma unroll
    for (int c = 0; c < 4; ++c) {
        short8 b0 = as_s8(Wt[(size_t)(c * 16 + l15) * 8 + lq]);
        short8 b1 = as_s8(Wt[(size_t)(c * 16 + l15) * 8 + 4 + lq]);
        f32x4 acc = {0.f, 0.f, 0.f, 0.f};
        acc = __builtin_amdgcn_mfma_f32_16x16x32_bf16(a0, b0, acc, 0, 0, 0);
        acc = __builtin_amdgcn_mfma_f32_16x16x32_bf16(a1, b1, acc, 0, 0, 0);
#pragma unroll
        for (int r = 0; r < 4; ++r) {
            int row = orow0 + r;
            if (row < n)
                t[(size_t)row * 64 + c * 16 + l15] = (unsigned short)bf16rne(acc[r] * dn[r]);
        }
    }
}

// ---------------- fused: gather(t_in)+relu+bias -> h-tile(LDS) -> MFMA -> t_out ----
// Block = 64 nodes, 256 threads (r10/r13 proven shape). Phase 1: 16 groups x 4
// rounds, uniform 8-deep unroll; row ranges prefetched. Phase 2: 4 waves MFMA.
#define ACC4(v) \
    acc.x += lo16(v.x); acc.y += hi16(v.x); acc.z += lo16(v.y); acc.w += hi16(v.y);

template<int NC>
__global__ __launch_bounds__(256) void k_fused(
    const int* __restrict__ row_beg, const int* __restrict__ row_end,
    const int* __restrict__ csr_src,
    const uint2* __restrict__ t_in,      // bf16 [n][64] as uint2 (4 feats)
    const float* __restrict__ dis, const float* __restrict__ bias,
    const uint4* __restrict__ Wt,        // bf16 W^T, 8 uint4 per col
    unsigned short* __restrict__ t_out, int n) {
    __shared__ unsigned short htile[64][72];   // 144B row stride

    int tdx = threadIdx.x;
    int grp = tdx >> 4, l15 = tdx & 15;
    int grpbase = tdx & 48;                    // wave-lane base of this 16-lane group
    int nblk0 = blockIdx.x * 64;

    const float4 bb = *(const float4*)(bias + l15 * 4);

    // prefetch all 4 rounds' row ranges (8 independent loads, overlapped latency)
    int begs[4], ends[4];
#pragma unroll
    for (int rnd = 0; rnd < 4; ++rnd) {
        int node = nblk0 + rnd * 16 + grp;
        int nc = node < n ? node : n - 1;
        begs[rnd] = row_beg[nc];
        ends[rnd] = row_end[nc];
    }

    // ---- phase 1: gather 64 nodes (4 rounds of 16 groups) ----
#pragma unroll
    for (int rnd = 0; rnd < 4; ++rnd) {
        int nl = rnd * 16 + grp;
        int node = nblk0 + nl;
        uint2 hw = make_uint2(0u, 0u);
        if (node < n) {
            int beg = begs[rnd], end = ends[rnd];
            uint2 sv0 = t_in[(size_t)node * 16 + l15];             // self loop
            float4 acc = make_float4(lo16(sv0.x), hi16(sv0.x), lo16(sv0.y), hi16(sv0.y));
            for (int j0 = beg; j0 < end; j0 += 16) {
                int myj = j0 + l15;
                int sv  = (myj < end) ? csr_src[myj] : 0;
                int m   = end - j0; if (m > 16) m = 16;
                int k = 0;
                for (; k + 8 <= m; k += 8) {
                    int s0 = __shfl(sv, grpbase + k);
                    int s1 = __shfl(sv, grpbase + k + 1);
                    int s2 = __shfl(sv, grpbase + k + 2);
                    int s3 = __shfl(sv, grpbase + k + 3);
                    int s4 = __shfl(sv, grpbase + k + 4);
                    int s5 = __shfl(sv, grpbase + k + 5);
                    int s6 = __shfl(sv, grpbase + k + 6);
                    int s7 = __shfl(sv, grpbase + k + 7);
                    uint2 v0 = t_in[(size_t)s0 * 16 + l15];
                    uint2 v1 = t_in[(size_t)s1 * 16 + l15];
                    uint2 v2 = t_in[(size_t)s2 * 16 + l15];
                    uint2 v3 = t_in[(size_t)s3 * 16 + l15];
                    uint2 v4 = t_in[(size_t)s4 * 16 + l15];
                    uint2 v5 = t_in[(size_t)s5 * 16 + l15];
                    uint2 v6 = t_in[(size_t)s6 * 16 + l15];
                    uint2 v7 = t_in[(size_t)s7 * 16 + l15];
                    ACC4(v0) ACC4(v1) ACC4(v2) ACC4(v3)
                    ACC4(v4) ACC4(v5) ACC4(v6) ACC4(v7)
                }
                for (; k < m; ++k) {
                    int s0 = __shfl(sv, grpbase + k);
                    uint2 v0 = t_in[(size_t)s0 * 16 + l15];
                    ACC4(v0)
                }
            }
            float dn = dis[node];
            float ox = fmaxf(fmaf(dn, acc.x, bb.x), 0.f);
            float oy = fmaxf(fmaf(dn, acc.y, bb.y), 0.f);
            float oz = fmaxf(fmaf(dn, acc.z, bb.z), 0.f);
            float ow = fmaxf(fmaf(dn, acc.w, bb.w), 0.f);
            hw = make_uint2(pack2(ox, oy), pack2(oz, ow));
        }
        *(uint2*)&htile[nl][l15 * 4] = hw;
    }
    __syncthreads();

    // ---- phase 2: MFMA on the LDS h-tile ----
    int wave = tdx >> 6, lane = tdx & 63;
    int lq = lane >> 4;
    int rbase = wave * 16;
    short8 a0 = as_s8(*(const uint4*)&htile[rbase + l15][lq * 8]);
    short8 a1 = as_s8(*(const uint4*)&htile[rbase + l15][32 + lq * 8]);

    int orow0 = nblk0 + rbase + lq * 4;
    float dn[4];
#pragma unroll
    for (int r = 0; r < 4; ++r) {
        int rr = orow0 + r;
        dn[r] = (rr < n) ? dis[rr] : 0.f;
    }
#pragma unroll
    for (int c = 0; c < NC; ++c) {
        short8 b0 = as_s8(Wt[(size_t)(c * 16 + l15) * 8 + lq]);
        short8 b1 = as_s8(Wt[(size_t)(c * 16 + l15) * 8 + 4 + lq]);
        f32x4 acc = {0.f, 0.f, 0.f, 0.f};
        acc = __builtin_amdgcn_mfma_f32_16x16x32_bf16(a0, b0, acc, 0, 0, 0);
        acc = __builtin_amdgcn_mfma_f32_16x16x32_bf16(a1, b1, acc, 0, 0, 0);
#pragma unroll
        for (int r = 0; r < 4; ++r) {
            int row = orow0 + r;
            if (row < n)
                t_out[(size_t)row * (NC * 16) + c * 16 + l15] =
                    (unsigned short)bf16rne(acc[r] * dn[r]);
        }
    }
}

// ---- final gather: one node per 4 lanes; lane holds 4 of 16 feats. f32 out ----
__global__ void k_gather16(const int* __restrict__ row_beg, const int* __restrict__ row_end,
                           const int* __restrict__ csr_src,
                           const uint2* __restrict__ t2, const float* __restrict__ dis,
                           const float* __restrict__ b, float* __restrict__ out, int n) {
    int tid  = blockIdx.x * blockDim.x + threadIdx.x;
    int node = tid >> 2;
    if (node >= n) return;
    int lane3   = threadIdx.x & 3;
    int grpbase = threadIdx.x & 60;
    int beg = row_beg[node], end = row_end[node];

    uint2 sv0 = t2[(size_t)node * 4 + lane3];                  // self loop
    float4 acc = make_float4(lo16(sv0.x), hi16(sv0.x), lo16(sv0.y), hi16(sv0.y));

    for (int j0 = beg; j0 < end; j0 += 4) {
        int myj = j0 + lane3;
        int sv  = (myj < end) ? csr_src[myj] : 0;
        int m   = end - j0; if (m > 4) m = 4;
        int k = 0;
        for (; k + 2 <= m; k += 2) {
            int s0 = __shfl(sv, grpbase + k);
            int s1 = __shfl(sv, grpbase + k + 1);
            uint2 v0 = t2[(size_t)s0 * 4 + lane3];
            uint2 v1 = t2[(size_t)s1 * 4 + lane3];
            ACC4(v0) ACC4(v1)
        }
        for (; k < m; ++k) {
            int s0 = __shfl(sv, grpbase + k);
            uint2 v0 = t2[(size_t)s0 * 4 + lane3];
            ACC4(v0)
        }
    }
    float dn = dis[node];
    const float4 bb = *(const float4*)(b + lane3 * 4);
    float4 o;
    o.x = fmaf(dn, acc.x, bb.x);
    o.y = fmaf(dn, acc.y, bb.y);
    o.z = fmaf(dn, acc.z, bb.z);
    o.w = fmaf(dn, acc.w, bb.w);
    *(float4*)(out + (size_t)node * 16 + lane3 * 4) = o;
}

// ---------------- launch ----------------

extern "C" void kernel_launch(void* const* d_in, const int* in_sizes, int n_in,
                              void* d_out, int out_size, void* d_ws, size_t ws_size,
                              hipStream_t stream) {
    const float* x     = (const float*)d_in[0];
    const int*   ei    = (const int*)d_in[1];
    const float* W_in  = (const float*)d_in[2];
    const float* b_in  = (const float*)d_in[3];
    const float* W_h   = (const float*)d_in[4];
    const float* b_h   = (const float*)d_in[5];
    const float* W_out = (const float*)d_in[6];
    const float* b_out = (const float*)d_in[7];

    const int n = in_sizes[0] / 64;
    const int e = in_sizes[1] / 2;
    const int* src = ei;
    const int* dst = ei + e;
    const int nb = (n + BKT_NODES - 1) / BKT_NODES;   // 782
    if (nb > NBMAX) return;

    char* ws = (char*)d_ws;
    size_t off = 0;
    auto alloc = [&](size_t bytes) { void* p = ws + off; off += (bytes + 255) & ~(size_t)255; return p; };
    float*          dis       = (float*)alloc((size_t)n * 4);
    unsigned short* t_a       = (unsigned short*)alloc((size_t)n * 64 * 2);
    unsigned short* t_b       = (unsigned short*)alloc((size_t)n * 64 * 2);
    unsigned short* Wt        = (unsigned short*)alloc(13312 * 2);
    int*            gcursor   = (int*)alloc((size_t)nb * 4);
    unsigned*       bkt_edges = (unsigned*)alloc((size_t)nb * CAP * 4);
    int*            row_beg   = (int*)alloc((size_t)n * 4);
    int*            row_end   = (int*)alloc((size_t)n * 4);
    int*            csr_src   = (int*)alloc((size_t)nb * CAP * 4);

    const int nblk_b = (e + EB - 1) / EB;     // 98
    const int nblk_f = (n + 63) / 64;

    // ---- prep (weights->bf16^T, gcursor=window starts) + CSR build ----
    k_prep <<<52, 256, 0, stream>>>(W_in, W_h, W_out, Wt, gcursor, nb);
    k_binB <<<nblk_b, 512, 0, stream>>>(src, dst, e, nb, gcursor, bkt_edges);
    k_bsort<<<nb, 256, 0, stream>>>(gcursor, bkt_edges, row_beg, row_end, csr_src, dis, n);

    // ---- layer 1: t1 = dis * (x @ W_in) ----
    k_mmfma_x<<<nblk_f, 256, 0, stream>>>((const float4*)x, (const uint4*)Wt, dis, t_a, n);

    // ---- layer 2: h1 = relu(agg(t1)+b_in); t2 = dis*(h1 @ W_h0) ----
    k_fused<4><<<nblk_f, 256, 0, stream>>>(row_beg, row_end, csr_src, (const uint2*)t_a,
                                           dis, b_in, (const uint4*)(Wt + 4096), t_b, n);
    // ---- layer 3 ----
    k_fused<4><<<nblk_f, 256, 0, stream>>>(row_beg, row_end, csr_src, (const uint2*)t_b,
                                           dis, b_h, (const uint4*)(Wt + 8192), t_a, n);
    // ---- layer 4 (16 cols) ----
    k_fused<1><<<nblk_f, 256, 0, stream>>>(row_beg, row_end, csr_src, (const uint2*)t_a,
                                           dis, b_h + 64, (const uint4*)(Wt + 12288), t_b, n);
    // ---- final: out = dis*agg(t4) + b_out (f32) ----
    k_gather16<<<(n * 4 + 255) / 256, 256, 0, stream>>>(row_beg, row_end, csr_src,
                                                        (const uint2*)t_b, dis, b_out,
                                                        (float*)d_out, n);
}

// Round 15
// 200.389 us; speedup vs baseline: 1.0322x; 1.0322x over previous
//
#include <hip/hip_runtime.h>

// GCN: 4 layers (64->64->64->64->16), N=100k nodes, E=1.6M edges (+ self loops).
// out[i] = dis[i] * ( sum_{src->i} t[src] + t[i] ) + b,  t = dis * (h @ W)
// Round 15: exact revert to the r13 configuration (200.7us, best measured).
// r14's two-pass binB regressed (98 blocks -> 6.7% occupancy). Structure:
//  - CSR build: fixed-capacity bucket windows (128 nodes, CAP=4096), one-pass
//    register-staged binning, per-bucket counting sort -> gapped row_beg/end.
//  - Layers: MFMA 16x16x32 bf16; gather(l)+relu+bias -> LDS h-tile -> MFMA(l+1)
//    fused per 64-node block (h never touches global).
//  - k_fused is pinned at ~44.6us across 5 structural variants: 82MB of
//    per-XCD-deduplicated random 128B row fetches at the ~2TB/s random-granule
//    HBM rate. This is the structural floor of the dst-partitioned gather.

#define BKT_SHIFT 7
#define BKT_NODES 128
#define NBMAX 800               // max buckets (n <= 102400)
#define CAP 4096                // edges per bucket window (mean 2046, max ~2300)
#define EPT 16                  // edges per thread in binning

typedef __attribute__((ext_vector_type(8))) short short8;   // 8 bf16 (4 VGPRs)
typedef __attribute__((ext_vector_type(4))) float f32x4;

union U4S8 { uint4 u; short8 s; };
__device__ __forceinline__ short8 as_s8(uint4 u) { U4S8 c; c.u = u; return c.s; }

// ---- bf16 helpers ----
__device__ __forceinline__ unsigned bf16rne(float f) {
    unsigned u = __float_as_uint(f);
    return (u + 0x7FFFu + ((u >> 16) & 1u)) >> 16;
}
__device__ __forceinline__ unsigned pack2(float a, float b) {
    return bf16rne(a) | (bf16rne(b) << 16);
}
__device__ __forceinline__ float lo16(unsigned u) { return __uint_as_float(u << 16); }
__device__ __forceinline__ float hi16(unsigned u) { return __uint_as_float(u & 0xFFFF0000u); }

// ---- prep: weights f32 -> bf16 transposed + gcursor init ----
__global__ void k_prep(const float* __restrict__ W_in, const float* __restrict__ W_h,
                       const float* __restrict__ W_out, unsigned short* __restrict__ Wt,
                       int* __restrict__ gcursor, int nb) {
    int i = blockIdx.x * 256 + threadIdx.x;
    if (i < 12288) {
        int w = i >> 12, r = i & 4095;
        int col = r >> 6, k = r & 63;
        const float* Wp = (w == 0) ? W_in : W_h + (size_t)(w - 1) * 4096;
        Wt[i] = (unsigned short)bf16rne(Wp[(size_t)k * 64 + col]);
    } else if (i < 13312) {
        int r = i - 12288;
        int col = r >> 6, k = r & 63;
        Wt[i] = (unsigned short)bf16rne(W_out[(size_t)k * 16 + col]);
    }
    if (i < nb) gcursor[i] = i * CAP;
}

// ---- place edges into fixed bucket windows: bkt_edges[p] = (src<<7)|(dst&127) ----
__global__ __launch_bounds__(256) void k_binB(const int* __restrict__ src,
                                              const int* __restrict__ dst, int e, int nb,
                                              int* __restrict__ gcursor,
                                              unsigned* __restrict__ bkt_edges) {
    __shared__ int lcnt[NBMAX];
    __shared__ int lbase[NBMAX];
    int tdx = threadIdx.x;
    for (int i = tdx; i < nb; i += 256) lcnt[i] = 0;
    __syncthreads();
    int base = blockIdx.x * (256 * EPT);
    unsigned val[EPT];
    int bkt[EPT];
#pragma unroll
    for (int k = 0; k < EPT; ++k) {
        int i = base + k * 256 + tdx;
        if (i < e) {
            int s_ = src[i], d_ = dst[i];
            val[k] = ((unsigned)s_ << BKT_SHIFT) | (unsigned)(d_ & (BKT_NODES - 1));
            bkt[k] = d_ >> BKT_SHIFT;
            atomicAdd(&lcnt[bkt[k]], 1);
        } else bkt[k] = -1;
    }
    __syncthreads();
    for (int b = tdx; b < nb; b += 256) {
        int c = lcnt[b];
        lbase[b] = c ? atomicAdd(&gcursor[b], c) : 0;
        lcnt[b] = 0;
    }
    __syncthreads();
#pragma unroll
    for (int k = 0; k < EPT; ++k) {
        if (bkt[k] >= 0) {
            int o = atomicAdd(&lcnt[bkt[k]], 1);
            bkt_edges[lbase[bkt[k]] + o] = val[k];
        }
    }
}

// ---- per-bucket counting sort -> row_beg/row_end CSR (gapped) + dis ----
__global__ __launch_bounds__(256) void k_bsort(
    const int* __restrict__ gcursor, const unsigned* __restrict__ bkt_edges,
    int* __restrict__ row_beg, int* __restrict__ row_end, int* __restrict__ csr_src,
    float* __restrict__ dis, int n) {
    __shared__ int hist[BKT_NODES];
    __shared__ int sc[BKT_NODES];
    __shared__ int cur[BKT_NODES];
    int b = blockIdx.x, tdx = threadIdx.x;
    int beg = b * CAP;
    int end = gcursor[b];               // final cursor = beg + count
    if (tdx < BKT_NODES) hist[tdx] = 0;
    __syncthreads();
    for (int j = beg + tdx; j < end; j += 256)
        atomicAdd(&hist[bkt_edges[j] & (BKT_NODES - 1)], 1);
    __syncthreads();
    if (tdx < BKT_NODES) sc[tdx] = hist[tdx];
    __syncthreads();
    for (int off = 1; off < BKT_NODES; off <<= 1) {
        int v = (tdx < BKT_NODES && tdx >= off) ? sc[tdx - off] : 0;
        __syncthreads();
        if (tdx < BKT_NODES && tdx >= off) sc[tdx] += v;
        __syncthreads();
    }
    if (tdx < BKT_NODES) {
        int node = b * BKT_NODES + tdx;
        if (node < n) {
            int pos = beg + sc[tdx] - hist[tdx];   // exclusive prefix
            row_beg[node] = pos;
            row_end[node] = pos + hist[tdx];
            cur[tdx] = pos;
            dis[node] = rsqrtf((float)(hist[tdx] + 1));   // +1 self loop
        }
    }
    __syncthreads();
    for (int j = beg + tdx; j < end; j += 256) {
        unsigned ev = bkt_edges[j];
        int p = atomicAdd(&cur[ev & (BKT_NODES - 1)], 1);
        csr_src[p] = (int)(ev >> BKT_SHIFT);
    }
}

// ---------------- layer-1 MFMA: t = dis * (x_f32 @ W_in) ----------------
__global__ __launch_bounds__(256) void k_mmfma_x(
    const float4* __restrict__ x4,       // f32 [n][16 float4]
    const uint4* __restrict__ Wt,        // bf16 W^T, 8 uint4 per col
    const float* __restrict__ dis,
    unsigned short* __restrict__ t, int n) {
    int wave = threadIdx.x >> 6, lane = threadIdx.x & 63;
    int base = blockIdx.x * 64 + wave * 16;
    if (base >= n) return;
    int l15 = lane & 15, lq = lane >> 4;

    int arow = base + l15;
    int ac = arow < n ? arow : n - 1;            // clamp: OOB rows never stored
    const float4* xr = x4 + (size_t)ac * 16;
    float4 f0 = xr[lq * 2], f1 = xr[lq * 2 + 1];         // feats lq*8..+8
    float4 f2 = xr[8 + lq * 2], f3 = xr[9 + lq * 2];     // feats 32+lq*8..+8
    uint4 u0, u1;
    u0.x = pack2(f0.x, f0.y); u0.y = pack2(f0.z, f0.w);
    u0.z = pack2(f1.x, f1.y); u0.w = pack2(f1.z, f1.w);
    u1.x = pack2(f2.x, f2.y); u1.y = pack2(f2.z, f2.w);
    u1.z = pack2(f3.x, f3.y); u1.w = pack2(f3.z, f3.w);
    short8 a0 = as_s8(u0), a1 = as_s8(u1);

    int orow0 = base + lq * 4;
    float dn[4];
#pragma unroll
    for (int r = 0; r < 4; ++r) {
        int rr = orow0 + r;
        dn[r] = (rr < n) ? dis[rr] : 0.f;
    }
#pragma unroll
    for (int c = 0; c < 4; ++c) {
        short8 b0 = as_s8(Wt[(size_t)(c * 16 + l15) * 8 + lq]);
        short8 b1 = as_s8(Wt[(size_t)(c * 16 + l15) * 8 + 4 + lq]);
        f32x4 acc = {0.f, 0.f, 0.f, 0.f};
        acc = __builtin_amdgcn_mfma_f32_16x16x32_bf16(a0, b0, acc, 0, 0, 0);
        acc = __builtin_amdgcn_mfma_f32_16x16x32_bf16(a1, b1, acc, 0, 0, 0);
#pragma unroll
        for (int r = 0; r < 4; ++r) {
            int row = orow0 + r;
            if (row < n)
                t[(size_t)row * 64 + c * 16 + l15] = (unsigned short)bf16rne(acc[r] * dn[r]);
        }
    }
}

// ---------------- fused: gather(t_in)+relu+bias -> h-tile(LDS) -> MFMA -> t_out ----
// Block = 64 nodes, 256 threads. Phase 1: 16 groups x 4 rounds, uniform 8-deep
// unroll; row ranges prefetched. Phase 2: 4 waves MFMA.
#define ACC4(v) \
    acc.x += lo16(v.x); acc.y += hi16(v.x); acc.z += lo16(v.y); acc.w += hi16(v.y);

template<int NC>
__global__ __launch_bounds__(256) void k_fused(
    const int* __restrict__ row_beg, const int* __restrict__ row_end,
    const int* __restrict__ csr_src,
    const uint2* __restrict__ t_in,      // bf16 [n][64] as uint2 (4 feats)
    const float* __restrict__ dis, const float* __restrict__ bias,
    const uint4* __restrict__ Wt,        // bf16 W^T, 8 uint4 per col
    unsigned short* __restrict__ t_out, int n) {
    __shared__ unsigned short htile[64][72];   // 144B row stride

    int tdx = threadIdx.x;
    int grp = tdx >> 4, l15 = tdx & 15;
    int grpbase = tdx & 48;                    // wave-lane base of this 16-lane group
    int nblk0 = blockIdx.x * 64;

    const float4 bb = *(const float4*)(bias + l15 * 4);

    // prefetch all 4 rounds' row ranges (8 independent loads, overlapped latency)
    int begs[4], ends[4];
#pragma unroll
    for (int rnd = 0; rnd < 4; ++rnd) {
        int node = nblk0 + rnd * 16 + grp;
        int nc = node < n ? node : n - 1;
        begs[rnd] = row_beg[nc];
        ends[rnd] = row_end[nc];
    }

    // ---- phase 1: gather 64 nodes (4 rounds of 16 groups) ----
#pragma unroll
    for (int rnd = 0; rnd < 4; ++rnd) {
        int nl = rnd * 16 + grp;
        int node = nblk0 + nl;
        uint2 hw = make_uint2(0u, 0u);
        if (node < n) {
            int beg = begs[rnd], end = ends[rnd];
            uint2 sv0 = t_in[(size_t)node * 16 + l15];             // self loop
            float4 acc = make_float4(lo16(sv0.x), hi16(sv0.x), lo16(sv0.y), hi16(sv0.y));
            for (int j0 = beg; j0 < end; j0 += 16) {
                int myj = j0 + l15;
                int sv  = (myj < end) ? csr_src[myj] : 0;
                int m   = end - j0; if (m > 16) m = 16;
                int k = 0;
                for (; k + 8 <= m; k += 8) {
                    int s0 = __shfl(sv, grpbase + k);
                    int s1 = __shfl(sv, grpbase + k + 1);
                    int s2 = __shfl(sv, grpbase + k + 2);
                    int s3 = __shfl(sv, grpbase + k + 3);
                    int s4 = __shfl(sv, grpbase + k + 4);
                    int s5 = __shfl(sv, grpbase + k + 5);
                    int s6 = __shfl(sv, grpbase + k + 6);
                    int s7 = __shfl(sv, grpbase + k + 7);
                    uint2 v0 = t_in[(size_t)s0 * 16 + l15];
                    uint2 v1 = t_in[(size_t)s1 * 16 + l15];
                    uint2 v2 = t_in[(size_t)s2 * 16 + l15];
                    uint2 v3 = t_in[(size_t)s3 * 16 + l15];
                    uint2 v4 = t_in[(size_t)s4 * 16 + l15];
                    uint2 v5 = t_in[(size_t)s5 * 16 + l15];
                    uint2 v6 = t_in[(size_t)s6 * 16 + l15];
                    uint2 v7 = t_in[(size_t)s7 * 16 + l15];
                    ACC4(v0) ACC4(v1) ACC4(v2) ACC4(v3)
                    ACC4(v4) ACC4(v5) ACC4(v6) ACC4(v7)
                }
                for (; k < m; ++k) {
                    int s0 = __shfl(sv, grpbase + k);
                    uint2 v0 = t_in[(size_t)s0 * 16 + l15];
                    ACC4(v0)
                }
            }
            float dn = dis[node];
            float ox = fmaxf(fmaf(dn, acc.x, bb.x), 0.f);
            float oy = fmaxf(fmaf(dn, acc.y, bb.y), 0.f);
            float oz = fmaxf(fmaf(dn, acc.z, bb.z), 0.f);
            float ow = fmaxf(fmaf(dn, acc.w, bb.w), 0.f);
            hw = make_uint2(pack2(ox, oy), pack2(oz, ow));
        }
        *(uint2*)&htile[nl][l15 * 4] = hw;
    }
    __syncthreads();

    // ---- phase 2: MFMA on the LDS h-tile ----
    int wave = tdx >> 6, lane = tdx & 63;
    int lq = lane >> 4;
    int rbase = wave * 16;
    short8 a0 = as_s8(*(const uint4*)&htile[rbase + l15][lq * 8]);
    short8 a1 = as_s8(*(const uint4*)&htile[rbase + l15][32 + lq * 8]);

    int orow0 = nblk0 + rbase + lq * 4;
    float dn[4];
#pragma unroll
    for (int r = 0; r < 4; ++r) {
        int rr = orow0 + r;
        dn[r] = (rr < n) ? dis[rr] : 0.f;
    }
#pragma unroll
    for (int c = 0; c < NC; ++c) {
        short8 b0 = as_s8(Wt[(size_t)(c * 16 + l15) * 8 + lq]);
        short8 b1 = as_s8(Wt[(size_t)(c * 16 + l15) * 8 + 4 + lq]);
        f32x4 acc = {0.f, 0.f, 0.f, 0.f};
        acc = __builtin_amdgcn_mfma_f32_16x16x32_bf16(a0, b0, acc, 0, 0, 0);
        acc = __builtin_amdgcn_mfma_f32_16x16x32_bf16(a1, b1, acc, 0, 0, 0);
#pragma unroll
        for (int r = 0; r < 4; ++r) {
            int row = orow0 + r;
            if (row < n)
                t_out[(size_t)row * (NC * 16) + c * 16 + l15] =
                    (unsigned short)bf16rne(acc[r] * dn[r]);
        }
    }
}

// ---- final gather: one node per 4 lanes; lane holds 4 of 16 feats. f32 out ----
__global__ void k_gather16(const int* __restrict__ row_beg, const int* __restrict__ row_end,
                           const int* __restrict__ csr_src,
                           const uint2* __restrict__ t2, const float* __restrict__ dis,
                           const float* __restrict__ b, float* __restrict__ out, int n) {
    int tid  = blockIdx.x * blockDim.x + threadIdx.x;
    int node = tid >> 2;
    if (node >= n) return;
    int lane3   = threadIdx.x & 3;
    int grpbase = threadIdx.x & 60;
    int beg = row_beg[node], end = row_end[node];

    uint2 sv0 = t2[(size_t)node * 4 + lane3];                  // self loop
    float4 acc = make_float4(lo16(sv0.x), hi16(sv0.x), lo16(sv0.y), hi16(sv0.y));

    for (int j0 = beg; j0 < end; j0 += 4) {
        int myj = j0 + lane3;
        int sv  = (myj < end) ? csr_src[myj] : 0;
        int m   = end - j0; if (m > 4) m = 4;
        int k = 0;
        for (; k + 2 <= m; k += 2) {
            int s0 = __shfl(sv, grpbase + k);
            int s1 = __shfl(sv, grpbase + k + 1);
            uint2 v0 = t2[(size_t)s0 * 4 + lane3];
            uint2 v1 = t2[(size_t)s1 * 4 + lane3];
            ACC4(v0) ACC4(v1)
        }
        for (; k < m; ++k) {
            int s0 = __shfl(sv, grpbase + k);
            uint2 v0 = t2[(size_t)s0 * 4 + lane3];
            ACC4(v0)
        }
    }
    float dn = dis[node];
    const float4 bb = *(const float4*)(b + lane3 * 4);
    float4 o;
    o.x = fmaf(dn, acc.x, bb.x);
    o.y = fmaf(dn, acc.y, bb.y);
    o.z = fmaf(dn, acc.z, bb.z);
    o.w = fmaf(dn, acc.w, bb.w);
    *(float4*)(out + (size_t)node * 16 + lane3 * 4) = o;
}

// ---------------- launch ----------------

extern "C" void kernel_launch(void* const* d_in, const int* in_sizes, int n_in,
                              void* d_out, int out_size, void* d_ws, size_t ws_size,
                              hipStream_t stream) {
    const float* x     = (const float*)d_in[0];
    const int*   ei    = (const int*)d_in[1];
    const float* W_in  = (const float*)d_in[2];
    const float* b_in  = (const float*)d_in[3];
    const float* W_h   = (const float*)d_in[4];
    const float* b_h   = (const float*)d_in[5];
    const float* W_out = (const float*)d_in[6];
    const float* b_out = (const float*)d_in[7];

    const int n = in_sizes[0] / 64;
    const int e = in_sizes[1] / 2;
    const int* src = ei;
    const int* dst = ei + e;
    const int nb = (n + BKT_NODES - 1) / BKT_NODES;   // 782
    if (nb > NBMAX) return;

    char* ws = (char*)d_ws;
    size_t off = 0;
    auto alloc = [&](size_t bytes) { void* p = ws + off; off += (bytes + 255) & ~(size_t)255; return p; };
    float*          dis       = (float*)alloc((size_t)n * 4);
    unsigned short* t_a       = (unsigned short*)alloc((size_t)n * 64 * 2);
    unsigned short* t_b       = (unsigned short*)alloc((size_t)n * 64 * 2);
    unsigned short* Wt        = (unsigned short*)alloc(13312 * 2);
    int*            gcursor   = (int*)alloc((size_t)nb * 4);
    unsigned*       bkt_edges = (unsigned*)alloc((size_t)nb * CAP * 4);
    int*            row_beg   = (int*)alloc((size_t)n * 4);
    int*            row_end   = (int*)alloc((size_t)n * 4);
    int*            csr_src   = (int*)alloc((size_t)nb * CAP * 4);

    const int nblk_e = (e + 256 * EPT - 1) / (256 * EPT);   // 391
    const int nblk_f = (n + 63) / 64;

    // ---- prep (weights->bf16^T, gcursor=window starts) + CSR build ----
    k_prep <<<52, 256, 0, stream>>>(W_in, W_h, W_out, Wt, gcursor, nb);
    k_binB <<<nblk_e, 256, 0, stream>>>(src, dst, e, nb, gcursor, bkt_edges);
    k_bsort<<<nb, 256, 0, stream>>>(gcursor, bkt_edges, row_beg, row_end, csr_src, dis, n);

    // ---- layer 1: t1 = dis * (x @ W_in) ----
    k_mmfma_x<<<nblk_f, 256, 0, stream>>>((const float4*)x, (const uint4*)Wt, dis, t_a, n);

    // ---- layer 2: h1 = relu(agg(t1)+b_in); t2 = dis*(h1 @ W_h0) ----
    k_fused<4><<<nblk_f, 256, 0, stream>>>(row_beg, row_end, csr_src, (const uint2*)t_a,
                                           dis, b_in, (const uint4*)(Wt + 4096), t_b, n);
    // ---- layer 3 ----
    k_fused<4><<<nblk_f, 256, 0, stream>>>(row_beg, row_end, csr_src, (const uint2*)t_b,
                                           dis, b_h, (const uint4*)(Wt + 8192), t_a, n);
    // ---- layer 4 (16 cols) ----
    k_fused<1><<<nblk_f, 256, 0, stream>>>(row_beg, row_end, csr_src, (const uint2*)t_a,
                                           dis, b_h + 64, (const uint4*)(Wt + 12288), t_b, n);
    // ---- final: out = dis*agg(t4) + b_out (f32) ----
    k_gather16<<<(n * 4 + 255) / 256, 256, 0, stream>>>(row_beg, row_end, csr_src,
                                                        (const uint2*)t_b, dis, b_out,
                                                        (float*)d_out, n);
}